// Round 1
// baseline (13993.869 us; speedup 1.0000x reference)
//
#include <hip/hip_runtime.h>
#include <hip/hip_fp16.h>

// Decoder: persistent cooperative-style kernel, 128 blocks x 512 threads,
// 48 steps x {attention, LSTM1, LSTM2} with custom device-scope grid barrier.
// All math fp32 (no fp32 MFMA on CDNA4); optional fp16 copy of encoder_outputs
// for the ctx stream (picked on host from ws_size).

#define WS_OFF_KEYST   0UL
#define WS_OFF_WBT     16777216UL
#define WS_OFF_WCT     20971520UL
#define WS_OFF_W1T     23068672UL
#define WS_OFF_LIN     23330816UL
#define WS_OFF_H1      23724032UL
#define WS_OFF_H2      23986176UL
#define WS_OFF_C1      24248320UL
#define WS_OFF_C2      24379392UL
#define WS_OFF_BAR     24510464UL
#define WS_OFF_ENCH    24510720UL
#define WS_CORE        24510720UL
#define WS_FULL        58065152UL

static __device__ __forceinline__ float fast_tanh(float x){
    float e = __expf(2.0f*x);                       // v_exp; inf-safe: ->1/-1
    return 1.0f - 2.0f*__builtin_amdgcn_rcpf(e + 1.0f);
}
static __device__ __forceinline__ float fast_sigm(float x){
    return __builtin_amdgcn_rcpf(1.0f + __expf(-x));
}

// Device-scope sense-reversing grid barrier. Grid=128 blocks <= 256 CUs so all
// blocks are resident by construction. __threadfence (agent fence) before
// arrival makes each thread's global writes visible; trailing fence
// invalidates vL1 so post-barrier reads see other XCDs' writes.
static __device__ __forceinline__ void gbar(int* bar, int nblk, int* lsense){
    __threadfence();
    __syncthreads();
    if(threadIdx.x == 0){
        int target = (*lsense) ^ 1;
        int prev = __hip_atomic_fetch_add(&bar[0], 1, __ATOMIC_ACQ_REL, __HIP_MEMORY_SCOPE_AGENT);
        if(prev == nblk - 1){
            __hip_atomic_store(&bar[0], 0, __ATOMIC_RELAXED, __HIP_MEMORY_SCOPE_AGENT);
            __hip_atomic_store(&bar[16], target, __ATOMIC_RELEASE, __HIP_MEMORY_SCOPE_AGENT);
        } else {
            while(__hip_atomic_load(&bar[16], __ATOMIC_ACQUIRE, __HIP_MEMORY_SCOPE_AGENT) != target){
                __builtin_amdgcn_s_sleep(2);
            }
        }
    }
    *lsense ^= 1;
    __syncthreads();
    __threadfence();
}

// ---------------- setup: weight transposes, state init, barrier init, enc->fp16
__global__ void setup_kernel(
    const float* __restrict__ Wx1, const float* __restrict__ Wh1,
    const float* __restrict__ Wx2, const float* __restrict__ Wh2,
    const float* __restrict__ W1,
    const float* __restrict__ h1_in, const float* __restrict__ c1_in,
    const float* __restrict__ h2_in, const float* __restrict__ c2_in,
    const float* __restrict__ enc,
    float* __restrict__ Wbt, float* __restrict__ Wct, float* __restrict__ W1t,
    float* __restrict__ h1b, float* __restrict__ h2b,
    float* __restrict__ c1b, float* __restrict__ c2b,
    int* __restrict__ bar, __half* __restrict__ encH, long long total)
{
    long long id0 = (long long)blockIdx.x*blockDim.x + threadIdx.x;
    long long stride = (long long)gridDim.x*blockDim.x;
    for(long long id = id0; id < total; id += stride){
        if(id < 1048576LL){
            int c = (int)(id >> 10), k = (int)(id & 1023);
            int n = (c & 3)*256 + (c >> 2);
            Wbt[id] = (k < 768) ? Wx1[k*1024 + n] : Wh1[(k-768)*1024 + n];
        } else if(id < 1572864LL){
            long long i2 = id - 1048576LL;
            int c = (int)(i2 >> 9), k = (int)(i2 & 511);
            int n = (c & 3)*256 + (c >> 2);
            Wct[i2] = (k < 256) ? Wx2[k*1024 + n] : Wh2[(k-256)*1024 + n];
        } else if(id < 1638400LL){
            long long i3 = id - 1572864LL;
            int u = (int)(i3 >> 9), e = (int)(i3 & 511);
            W1t[i3] = W1[e*128 + u];
        } else if(id < 1769472LL){
            long long i4 = id - 1638400LL;
            int which = (int)(i4 >> 15), i = (int)(i4 & 32767);
            if(which == 0)      h1b[i] = h1_in[i];
            else if(which == 1) h2b[i] = h2_in[i];
            else if(which == 2) c1b[i] = c1_in[i];
            else                c2b[i] = c2_in[i];
        } else if(id < 1769536LL){
            bar[(int)(id - 1769472LL)] = 0;
        } else {
            long long i6 = id - 1769536LL;
            encH[i6] = __float2half(enc[i6]);
        }
    }
}

// ---------------- keys = enc @ W1 + b1, stored transposed keysT[b][u][s]
__global__ __launch_bounds__(256) void keys_kernel(
    const float* __restrict__ enc, const float* __restrict__ W1t,
    const float* __restrict__ b1, float* __restrict__ keysT)
{
    const int bb = blockIdx.x;            // 1024 blocks
    const int b  = bb >> 3, sq = bb & 7;
    const int tid = threadIdx.x;
    const int u = tid & 127, sh = tid >> 7;
    const int s0 = sq*32 + sh*16;
    float acc[16];
    #pragma unroll
    for(int i = 0; i < 16; ++i) acc[i] = 0.0f;
    const float* wp = W1t + (size_t)u*512;
    const float* xp = enc + (size_t)(b*256 + s0)*512;
    for(int e = 0; e < 512; e += 4){
        float4 wv = *(const float4*)(wp + e);
        #pragma unroll
        for(int i = 0; i < 16; ++i){
            float4 xv = *(const float4*)(xp + (size_t)i*512 + e);   // wave-broadcast
            acc[i] += wv.x*xv.x + wv.y*xv.y + wv.z*xv.z + wv.w*xv.w;
        }
    }
    const float bu = b1[u];
    float* op = keysT + (size_t)(b*128 + u)*256 + s0;
    #pragma unroll
    for(int i = 0; i < 16; ++i) op[i] = acc[i] + bu;
}

// ---------------- persistent decoder
__global__ __launch_bounds__(512) void decoder_main(
    const float* __restrict__ xdec, const float* __restrict__ embW, const float* __restrict__ embb,
    const float* __restrict__ W2, const float* __restrict__ b2,
    const float* __restrict__ V, const float* __restrict__ bVp,
    const float* __restrict__ Wo, const float* __restrict__ bop,
    const float* __restrict__ bl1, const float* __restrict__ bl2,
    const float* __restrict__ enc, const __half* __restrict__ encH,
    const float* __restrict__ keysT, const float* __restrict__ Wbt, const float* __restrict__ Wct,
    float* __restrict__ lin, float* h1, float* h2, float* c1, float* c2,
    int* bar, float* __restrict__ out, int useEncH)
{
    const int tid = threadIdx.x;
    const int bid = blockIdx.x;
    __shared__ float sh_h2[256];
    __shared__ float sh_q[128];
    __shared__ float sh_V[128];
    __shared__ float sh_qp[4][128];
    __shared__ float sh_part[2][256];
    __shared__ float sh_at[256];
    __shared__ float sh_red[16];
    __shared__ float sh_ctx[2][512];
    __shared__ float sh_z[32][33];

    if(tid < 128) sh_V[tid] = V[tid];
    const float bVv = bVp[0];
    const float bov = bop[0];

    // phase B/C tiling: 128 blocks = 4 batch-tiles(32) x 32 col-tiles(32)
    const int mt  = bid >> 5;
    const int jt  = bid & 31;
    const int nB  = tid & 31;
    const int bgB = tid >> 5;             // 16 groups -> 2 batches each
    const int cB  = jt*32 + nB;           // c = unit*4 + gate
    const float biasB = bl1[(cB & 3)*256 + (cB >> 2)];
    const float biasC = bl2[(cB & 3)*256 + (cB >> 2)];

    int lsense = 0;
    const int b = bid;                    // attention batch for this block

    for(int t = 0; t < 48; ++t){
        const int rpar = t & 1;
        const float* h1r = h1 + rpar*32768;
        float*       h1w = h1 + (rpar^1)*32768;
        const float* h2r = h2 + rpar*32768;
        float*       h2w = h2 + (rpar^1)*32768;

        // ---------------- PHASE A : attention (+pred of t-1, +emb) ----------------
        if(tid < 256){
            sh_h2[tid] = h2r[b*256 + tid];
            float x = xdec[b*48 + t];
            lin[b*768 + tid] = fmaxf(x*embW[tid] + embb[tid], 0.0f);   // emb relu
        }
        __syncthreads();
        if(tid < 256){                     // pred_{t-1} = h2 . Wo + bo
            float pv = sh_h2[tid]*Wo[tid];
            #pragma unroll
            for(int off = 32; off >= 1; off >>= 1) pv += __shfl_xor(pv, off, 64);
            if((tid & 63) == 0) sh_red[tid >> 6] = pv;
        }
        {                                  // q partials: 4 k-groups x 128 u
            const int u = tid & 127, kq = tid >> 7;
            float a = 0.0f;
            const int k0 = kq*64;
            #pragma unroll 4
            for(int k = k0; k < k0 + 64; ++k) a += sh_h2[k]*W2[k*128 + u];
            sh_qp[kq][u] = a;
        }
        __syncthreads();
        if(tid == 0 && t > 0)
            out[b*48 + (t-1)] = sh_red[0]+sh_red[1]+sh_red[2]+sh_red[3] + bov;
        if(tid < 128)
            sh_q[tid] = sh_qp[0][tid]+sh_qp[1][tid]+sh_qp[2][tid]+sh_qp[3][tid] + b2[tid];
        __syncthreads();
        {                                  // score partials: 2 u-halves x 256 s
            const int sA = tid & 255, uh = tid >> 8;
            const float* kp = keysT + (size_t)(b*128 + uh*64)*256 + sA;
            float a = 0.0f;
            #pragma unroll 4
            for(int ui = 0; ui < 64; ++ui)
                a += fast_tanh(kp[(size_t)ui*256] + sh_q[uh*64 + ui]) * sh_V[uh*64 + ui];
            sh_part[uh][sA] = a;
        }
        __syncthreads();
        float sc = 0.0f, mx = 0.0f, pv = 0.0f;
        if(tid < 256){
            sc = sh_part[0][tid] + sh_part[1][tid] + bVv;
            mx = sc;
            #pragma unroll
            for(int off = 32; off >= 1; off >>= 1) mx = fmaxf(mx, __shfl_xor(mx, off, 64));
            if((tid & 63) == 0) sh_red[tid >> 6] = mx;
        }
        __syncthreads();
        if(tid < 256){
            mx = fmaxf(fmaxf(sh_red[0], sh_red[1]), fmaxf(sh_red[2], sh_red[3]));
            pv = __expf(sc - mx);
            float su = pv;
            #pragma unroll
            for(int off = 32; off >= 1; off >>= 1) su += __shfl_xor(su, off, 64);
            if((tid & 63) == 0) sh_red[8 + (tid >> 6)] = su;
        }
        __syncthreads();
        if(tid < 256){
            float su = sh_red[8]+sh_red[9]+sh_red[10]+sh_red[11];
            sh_at[tid] = pv / su;
        }
        __syncthreads();
        {                                  // ctx: 2 e per thread, s split in halves
            const int e2 = tid & 255, sb = tid >> 8;
            const int e = e2*2;
            float a0 = 0.0f, a1 = 0.0f;
            if(useEncH){
                const __half* ep = encH + (size_t)(b*256 + sb*128)*512 + e;
                #pragma unroll 4
                for(int si = 0; si < 128; ++si){
                    float at = sh_at[sb*128 + si];
                    __half2 hv = *(const __half2*)(ep + (size_t)si*512);
                    float2 f = __half22float2(hv);
                    a0 += at*f.x; a1 += at*f.y;
                }
            } else {
                const float* ep = enc + (size_t)(b*256 + sb*128)*512 + e;
                #pragma unroll 4
                for(int si = 0; si < 128; ++si){
                    float at = sh_at[sb*128 + si];
                    float2 f = *(const float2*)(ep + (size_t)si*512);
                    a0 += at*f.x; a1 += at*f.y;
                }
            }
            sh_ctx[sb][e]   = a0;
            sh_ctx[sb][e+1] = a1;
        }
        __syncthreads();
        lin[b*768 + 256 + tid] = sh_ctx[0][tid] + sh_ctx[1][tid];

        gbar(bar, 128, &lsense);

        // ---------------- PHASE B : LSTM1 z = [emb,ctx]@Wx1 + h1@Wh1 + bl1 ----------------
        {
            const int b0 = mt*32 + bgB*2, b1i = b0 + 1;
            const float* wp = Wbt + (size_t)cB*1024;
            const float* x0 = lin + (size_t)b0*768;
            const float* x1 = lin + (size_t)b1i*768;
            float acc0 = biasB, acc1 = biasB;
            #pragma unroll 2
            for(int k = 0; k < 768; k += 4){
                float4 wv = *(const float4*)(wp + k);
                float4 p0 = *(const float4*)(x0 + k);
                float4 p1 = *(const float4*)(x1 + k);
                acc0 += wv.x*p0.x + wv.y*p0.y + wv.z*p0.z + wv.w*p0.w;
                acc1 += wv.x*p1.x + wv.y*p1.y + wv.z*p1.z + wv.w*p1.w;
            }
            const float* wh = wp + 768;
            const float* y0 = h1r + (size_t)b0*256;
            const float* y1 = h1r + (size_t)b1i*256;
            #pragma unroll 2
            for(int k = 0; k < 256; k += 4){
                float4 wv = *(const float4*)(wh + k);
                float4 p0 = *(const float4*)(y0 + k);
                float4 p1 = *(const float4*)(y1 + k);
                acc0 += wv.x*p0.x + wv.y*p0.y + wv.z*p0.z + wv.w*p0.w;
                acc1 += wv.x*p1.x + wv.y*p1.y + wv.z*p1.z + wv.w*p1.w;
            }
            sh_z[nB][bgB*2]   = acc0;
            sh_z[nB][bgB*2+1] = acc1;
        }
        __syncthreads();
        if(tid < 256){
            const int b_l = tid >> 3, j_l = tid & 7;
            float zi = sh_z[j_l*4+0][b_l];
            float zf = sh_z[j_l*4+1][b_l];
            float zg = sh_z[j_l*4+2][b_l];
            float zo = sh_z[j_l*4+3][b_l];
            float iv = fast_sigm(zi), fv = fast_sigm(zf);
            float gv = fast_tanh(zg), ov = fast_sigm(zo);
            const int idx = (mt*32 + b_l)*256 + (jt*8 + j_l);
            float cn = fv*c1[idx] + iv*gv;
            c1[idx] = cn;
            h1w[idx] = ov*fast_tanh(cn);
        }
        gbar(bar, 128, &lsense);

        // ---------------- PHASE C : LSTM2 z = h1n@Wx2 + h2@Wh2 + bl2 ----------------
        {
            const int b0 = mt*32 + bgB*2, b1i = b0 + 1;
            const float* wp = Wct + (size_t)cB*512;
            const float* x0 = h1w + (size_t)b0*256;
            const float* x1 = h1w + (size_t)b1i*256;
            float acc0 = biasC, acc1 = biasC;
            #pragma unroll 2
            for(int k = 0; k < 256; k += 4){
                float4 wv = *(const float4*)(wp + k);
                float4 p0 = *(const float4*)(x0 + k);
                float4 p1 = *(const float4*)(x1 + k);
                acc0 += wv.x*p0.x + wv.y*p0.y + wv.z*p0.z + wv.w*p0.w;
                acc1 += wv.x*p1.x + wv.y*p1.y + wv.z*p1.z + wv.w*p1.w;
            }
            const float* wh = wp + 256;
            const float* y0 = h2r + (size_t)b0*256;
            const float* y1 = h2r + (size_t)b1i*256;
            #pragma unroll 2
            for(int k = 0; k < 256; k += 4){
                float4 wv = *(const float4*)(wh + k);
                float4 p0 = *(const float4*)(y0 + k);
                float4 p1 = *(const float4*)(y1 + k);
                acc0 += wv.x*p0.x + wv.y*p0.y + wv.z*p0.z + wv.w*p0.w;
                acc1 += wv.x*p1.x + wv.y*p1.y + wv.z*p1.z + wv.w*p1.w;
            }
            sh_z[nB][bgB*2]   = acc0;
            sh_z[nB][bgB*2+1] = acc1;
        }
        __syncthreads();
        if(tid < 256){
            const int b_l = tid >> 3, j_l = tid & 7;
            float zi = sh_z[j_l*4+0][b_l];
            float zf = sh_z[j_l*4+1][b_l];
            float zg = sh_z[j_l*4+2][b_l];
            float zo = sh_z[j_l*4+3][b_l];
            float iv = fast_sigm(zi), fv = fast_sigm(zf);
            float gv = fast_tanh(zg), ov = fast_sigm(zo);
            const int idx = (mt*32 + b_l)*256 + (jt*8 + j_l);
            float cn = fv*c2[idx] + iv*gv;
            c2[idx] = cn;
            h2w[idx] = ov*fast_tanh(cn);
        }
        gbar(bar, 128, &lsense);
    }

    // final pred t=47: after step 47 the new h2 sits at parity 0 (h2 base)
    if(tid < 256){
        float pv = h2[b*256 + tid]*Wo[tid];
        #pragma unroll
        for(int off = 32; off >= 1; off >>= 1) pv += __shfl_xor(pv, off, 64);
        if((tid & 63) == 0) sh_red[tid >> 6] = pv;
    }
    __syncthreads();
    if(tid == 0)
        out[b*48 + 47] = sh_red[0]+sh_red[1]+sh_red[2]+sh_red[3] + bov;
}

extern "C" void kernel_launch(void* const* d_in, const int* in_sizes, int n_in,
                              void* d_out, int out_size, void* d_ws, size_t ws_size,
                              hipStream_t stream)
{
    const float* xdec = (const float*)d_in[0];
    const float* h1_in= (const float*)d_in[1];
    const float* c1_in= (const float*)d_in[2];
    const float* h2_in= (const float*)d_in[3];
    const float* c2_in= (const float*)d_in[4];
    const float* enc  = (const float*)d_in[5];
    const float* embW = (const float*)d_in[6];
    const float* embb = (const float*)d_in[7];
    const float* W1   = (const float*)d_in[8];
    const float* b1   = (const float*)d_in[9];
    const float* W2   = (const float*)d_in[10];
    const float* b2   = (const float*)d_in[11];
    const float* V    = (const float*)d_in[12];
    const float* bV   = (const float*)d_in[13];
    const float* Wx1  = (const float*)d_in[14];
    const float* Wh1  = (const float*)d_in[15];
    const float* bl1  = (const float*)d_in[16];
    const float* Wx2  = (const float*)d_in[17];
    const float* Wh2  = (const float*)d_in[18];
    const float* bl2  = (const float*)d_in[19];
    const float* Wo   = (const float*)d_in[20];
    const float* bo   = (const float*)d_in[21];

    if(ws_size < WS_CORE) return;   // cannot run without core scratch

    char* ws = (char*)d_ws;
    float* keysT = (float*)(ws + WS_OFF_KEYST);
    float* Wbt   = (float*)(ws + WS_OFF_WBT);
    float* Wct   = (float*)(ws + WS_OFF_WCT);
    float* W1t   = (float*)(ws + WS_OFF_W1T);
    float* lin   = (float*)(ws + WS_OFF_LIN);
    float* h1    = (float*)(ws + WS_OFF_H1);
    float* h2    = (float*)(ws + WS_OFF_H2);
    float* c1    = (float*)(ws + WS_OFF_C1);
    float* c2    = (float*)(ws + WS_OFF_C2);
    int*   bar   = (int*)  (ws + WS_OFF_BAR);
    __half* encH = (__half*)(ws + WS_OFF_ENCH);

    const int useEncH = (ws_size >= WS_FULL) ? 1 : 0;
    const long long total = useEncH ? 18546752LL : 1769536LL;

    hipLaunchKernelGGL(setup_kernel, dim3(4096), dim3(256), 0, stream,
        Wx1, Wh1, Wx2, Wh2, W1, h1_in, c1_in, h2_in, c2_in, enc,
        Wbt, Wct, W1t, h1, h2, c1, c2, bar, encH, total);

    hipLaunchKernelGGL(keys_kernel, dim3(1024), dim3(256), 0, stream,
        enc, W1t, b1, keysT);

    hipLaunchKernelGGL(decoder_main, dim3(128), dim3(512), 0, stream,
        xdec, embW, embb, W2, b2, V, bV, Wo, bo, bl1, bl2,
        enc, encH, keysT, Wbt, Wct, lin, h1, h2, c1, c2, bar,
        (float*)d_out, useEncH);
}

// Round 2
// 2802.738 us; speedup vs baseline: 4.9929x; 4.9929x over previous
//
#include <hip/hip_runtime.h>
#include <hip/hip_fp16.h>

#define AGENT __HIP_MEMORY_SCOPE_AGENT

typedef _Float16 v8h __attribute__((ext_vector_type(8)));
typedef float    v4f __attribute__((ext_vector_type(4)));

// ---- workspace map (bytes) ----
#define OFF_KEYSH  0UL            // __half [128][128][256]  = 8,388,608
#define OFF_WBT    8388608UL      // __half [1024 c][1024 k] = 2,097,152
#define OFF_WCT    10485760UL     // __half [1024 c][512 k]  = 1,048,576
#define OFF_W1T    11534336UL     // float  [128 u][512 e]   =   262,144
#define OFF_LIN    11796480UL     // uint   [128 b][384 dw]  =   196,608
#define OFF_H1     11993088UL     // uint   [2][128][128]    =   131,072
#define OFF_H2     12124160UL     // uint   [2][128][128]    =   131,072
#define OFF_CNT    12255232UL     // int[256]                =     1,024
#define WS_CORE    12256256UL
#define OFF_ENCH   12256256UL     // __half [128][256][512]  = 33,554,432
#define WS_FULL    45810688UL

static __device__ __forceinline__ float fast_tanh(float x){
    float e = __expf(2.0f*x);
    return 1.0f - 2.0f*__builtin_amdgcn_rcpf(e + 1.0f);
}
static __device__ __forceinline__ float fast_sigm(float x){
    return __builtin_amdgcn_rcpf(1.0f + __expf(-x));
}

// Fence-free grid barrier: all mutable cross-block data moves via relaxed
// agent-scope atomics (coherent at MALL); s_waitcnt(0) drains each wave's
// outstanding sc-flagged stores before arrival. No buffer_inv / wbl2 -> L2
// stays warm for read-only weights/keys/enc. One fresh counter per phase.
static __device__ __forceinline__ void gbar(int* cnt, int idx){
    __builtin_amdgcn_s_waitcnt(0);
    __syncthreads();
    if(threadIdx.x == 0){
        __hip_atomic_fetch_add(&cnt[idx], 1, __ATOMIC_RELAXED, AGENT);
        while(__hip_atomic_load(&cnt[idx], __ATOMIC_RELAXED, AGENT) < 128)
            __builtin_amdgcn_s_sleep(1);
    }
    __syncthreads();
}

// ---------------- setup: fp16 weight transposes, state packing, counters, encH
__global__ __launch_bounds__(256) void setup_kernel(
    const float* __restrict__ Wx1, const float* __restrict__ Wh1,
    const float* __restrict__ Wx2, const float* __restrict__ Wh2,
    const float* __restrict__ W1,
    const float* __restrict__ h1_in, const float* __restrict__ h2_in,
    const float* __restrict__ enc,
    __half* __restrict__ WbtH, __half* __restrict__ WctH, float* __restrict__ W1t,
    unsigned int* __restrict__ h1d, unsigned int* __restrict__ h2d,
    int* __restrict__ cnt, __half* __restrict__ encH, long long total)
{
    long long id0 = (long long)blockIdx.x*blockDim.x + threadIdx.x;
    long long stride = (long long)gridDim.x*blockDim.x;
    for(long long id = id0; id < total; id += stride){
        if(id < 1048576LL){                         // WbtH[c][k], c=4u+g, n=g*256+u
            int c = (int)(id >> 10), k = (int)(id & 1023);
            int n = (c & 3)*256 + (c >> 2);
            float v = (k < 768) ? Wx1[k*1024 + n] : Wh1[(k-768)*1024 + n];
            WbtH[id] = __float2half(v);
        } else if(id < 1572864LL){                  // WctH[c][k]
            long long i2 = id - 1048576LL;
            int c = (int)(i2 >> 9), k = (int)(i2 & 511);
            int n = (c & 3)*256 + (c >> 2);
            float v = (k < 256) ? Wx2[k*1024 + n] : Wh2[(k-256)*1024 + n];
            WctH[i2] = __float2half(v);
        } else if(id < 1638400LL){                  // W1t[u][e]
            long long i3 = id - 1572864LL;
            int u = (int)(i3 >> 9), e = (int)(i3 & 511);
            W1t[i3] = W1[e*128 + u];
        } else if(id < 1654784LL){                  // h1d parity 0, packed fp16 pairs
            long long i4 = id - 1638400LL;
            int b = (int)(i4 >> 7), j = (int)(i4 & 127);
            __half2 p = __floats2half2_rn(h1_in[b*256 + 2*j], h1_in[b*256 + 2*j + 1]);
            h1d[i4] = __builtin_bit_cast(unsigned int, p);
        } else if(id < 1671168LL){                  // h2d parity 0
            long long i5 = id - 1654784LL;
            int b = (int)(i5 >> 7), j = (int)(i5 & 127);
            __half2 p = __floats2half2_rn(h2_in[b*256 + 2*j], h2_in[b*256 + 2*j + 1]);
            h2d[i5] = __builtin_bit_cast(unsigned int, p);
        } else if(id < 1671424LL){
            cnt[(int)(id - 1671168LL)] = 0;
        } else {
            long long i6 = id - 1671424LL;
            encH[i6] = __float2half(enc[i6]);
        }
    }
}

// ---------------- keys = enc @ W1 + b1, transposed fp16 keysH[b][u][s]
__global__ __launch_bounds__(256) void keys_kernel(
    const float* __restrict__ enc, const float* __restrict__ W1t,
    const float* __restrict__ b1, __half* __restrict__ keysH)
{
    const int bb = blockIdx.x;            // 1024 blocks
    const int b  = bb >> 3, sq = bb & 7;
    const int tid = threadIdx.x;
    const int u = tid & 127, sh = tid >> 7;
    const int s0 = sq*32 + sh*16;
    float acc[16];
    #pragma unroll
    for(int i = 0; i < 16; ++i) acc[i] = 0.0f;
    const float* wp = W1t + (size_t)u*512;
    const float* xp = enc + (size_t)(b*256 + s0)*512;
    for(int e = 0; e < 512; e += 4){
        float4 wv = *(const float4*)(wp + e);
        #pragma unroll
        for(int i = 0; i < 16; ++i){
            float4 xv = *(const float4*)(xp + (size_t)i*512 + e);
            acc[i] += wv.x*xv.x + wv.y*xv.y + wv.z*xv.z + wv.w*xv.w;
        }
    }
    const float bu = b1[u];
    __half* op = keysH + (size_t)(b*128 + u)*256 + s0;
    #pragma unroll
    for(int i = 0; i < 16; ++i) op[i] = __float2half(acc[i] + bu);
}

// ---------------- persistent decoder: 128 blocks x 1024 threads
__global__ __launch_bounds__(1024) void decoder_main(
    const float* __restrict__ xdec, const float* __restrict__ embW, const float* __restrict__ embb,
    const float* __restrict__ W2, const float* __restrict__ b2,
    const float* __restrict__ V, const float* __restrict__ bVp,
    const float* __restrict__ Wo, const float* __restrict__ bop,
    const float* __restrict__ bl1, const float* __restrict__ bl2,
    const float* __restrict__ c1_in, const float* __restrict__ c2_in,
    const float* __restrict__ enc, const __half* __restrict__ encH,
    const __half* __restrict__ keysH,
    const __half* __restrict__ WbtH, const __half* __restrict__ WctH,
    unsigned int* linD, unsigned int* h1d, unsigned int* h2d,
    int* cnt, float* __restrict__ out, int useEncH)
{
    const int tid = threadIdx.x;
    const int ab  = blockIdx.x;              // attention batch for this block
    const int NT  = blockIdx.x >> 1;         // col tile: cols 16NT..16NT+15 (units 4NT..4NT+3)
    const int H   = blockIdx.x & 1;          // batch half: 64H..64H+63
    const int w    = tid >> 6;               // wave 0..15 (= K-split index)
    const int lane = tid & 63;
    const int cl   = lane & 15;              // MFMA m-row / n-col / C-col
    const int kg   = lane >> 4;              // MFMA k-quad
    const int uu   = lane >> 4;              // pointwise unit-local
    const int bl   = lane & 15;              // pointwise batch-local

    __shared__ float zb[16][16][20];         // per-wave z partial tiles
    __shared__ float sh_h2[256];
    __shared__ float sh_q[128];
    __shared__ float sh_qp[8][128];
    __shared__ float sh_sp[4][256];
    __shared__ float sh_at[256];
    __shared__ float sh_red[16];
    __shared__ float sh_ctxp[2][512];
    __shared__ float sh_V[128];

    if(tid < 128) sh_V[tid] = V[tid];
    const float bVv = bVp[0];
    const float bov = bop[0];

    // ---- weights resident in VGPRs for all 48 steps ----
    const __half* wbp = WbtH + ((size_t)(16*NT + cl)*1024 + w*64 + kg*8);
    v8h wb1a = __builtin_bit_cast(v8h, *(const uint4*)(wbp));
    v8h wb1b = __builtin_bit_cast(v8h, *(const uint4*)(wbp + 32));
    const __half* wcp = WctH + ((size_t)(16*NT + cl)*512 + w*32 + kg*8);
    v8h wc1  = __builtin_bit_cast(v8h, *(const uint4*)(wcp));

    // ---- per-lane cell state + gate biases (only waves 0..3 own pointwise) ----
    const int ug = 4*NT + uu;
    float bi1 = bl1[ug], bf1 = bl1[256+ug], bg1 = bl1[512+ug], bo1 = bl1[768+ug];
    float bi2 = bl2[ug], bf2 = bl2[256+ug], bg2 = bl2[512+ug], bo2 = bl2[768+ug];
    float c1r = 0.0f, c2r = 0.0f;
    if(w < 4){
        int bb = 64*H + 16*w + bl;
        c1r = c1_in[bb*256 + ug];
        c2r = c2_in[bb*256 + ug];
    }
    __syncthreads();

    for(int t = 0; t < 48; ++t){
        const int rpar = t & 1, wpar = rpar ^ 1;
        unsigned int* h1r = h1d + rpar*16384;
        unsigned int* h1w = h1d + wpar*16384;
        unsigned int* h2r = h2d + rpar*16384;
        unsigned int* h2w = h2d + wpar*16384;

        // ================= PHASE A : attention + pred(t-1) + emb =================
        if(tid < 128){
            unsigned int v = __hip_atomic_load(&h2r[ab*128 + tid], __ATOMIC_RELAXED, AGENT);
            float2 f = __half22float2(__builtin_bit_cast(__half2, v));
            sh_h2[2*tid] = f.x; sh_h2[2*tid+1] = f.y;
            float pv = f.x*Wo[2*tid] + f.y*Wo[2*tid+1];
            #pragma unroll
            for(int off = 32; off >= 1; off >>= 1) pv += __shfl_xor(pv, off);
            if((tid & 63) == 0) sh_red[8 + (tid >> 6)] = pv;
        }
        __syncthreads();
        if(tid == 0 && t > 0) out[ab*48 + (t-1)] = sh_red[8] + sh_red[9] + bov;
        {   // q partials: 8 k-groups x 128 u
            const int u = tid & 127, kq8 = tid >> 7;
            float a = 0.0f;
            const int k0 = kq8*32;
            #pragma unroll 8
            for(int k = k0; k < k0 + 32; ++k) a += sh_h2[k]*W2[k*128 + u];
            sh_qp[kq8][u] = a;
        }
        __syncthreads();
        if(tid < 128){
            float a = b2[tid];
            #pragma unroll
            for(int j = 0; j < 8; ++j) a += sh_qp[j][tid];
            sh_q[tid] = a;
        }
        __syncthreads();
        {   // score partials: 4 u-quarters x 256 s
            const int s = tid & 255, uq = tid >> 8;
            const __half* kp = keysH + ((size_t)(ab*128 + uq*32)*256 + s);
            float a = 0.0f;
            #pragma unroll 8
            for(int ui = 0; ui < 32; ++ui)
                a += fast_tanh(__half2float(kp[(size_t)ui*256]) + sh_q[uq*32 + ui]) * sh_V[uq*32 + ui];
            sh_sp[uq][s] = a;
        }
        __syncthreads();
        float sc = 0.0f, pexp = 0.0f;
        if(tid < 256){
            sc = sh_sp[0][tid] + sh_sp[1][tid] + sh_sp[2][tid] + sh_sp[3][tid] + bVv;
            float mx = sc;
            #pragma unroll
            for(int off = 32; off >= 1; off >>= 1) mx = fmaxf(mx, __shfl_xor(mx, off));
            if((tid & 63) == 0) sh_red[tid >> 6] = mx;
        }
        __syncthreads();
        if(tid < 256){
            float mx = fmaxf(fmaxf(sh_red[0], sh_red[1]), fmaxf(sh_red[2], sh_red[3]));
            pexp = __expf(sc - mx);
            float su = pexp;
            #pragma unroll
            for(int off = 32; off >= 1; off >>= 1) su += __shfl_xor(su, off);
            if((tid & 63) == 0) sh_red[4 + (tid >> 6)] = su;
        }
        __syncthreads();
        if(tid < 256){
            float su = sh_red[4] + sh_red[5] + sh_red[6] + sh_red[7];
            sh_at[tid] = pexp / su;
        }
        __syncthreads();
        {   // ctx partials: 2 s-halves x 512 e
            const int e = tid & 511, s2 = tid >> 9;
            float a = 0.0f;
            if(useEncH){
                const __half* ep = encH + ((size_t)(ab*256 + s2*128)*512 + e);
                #pragma unroll 8
                for(int si = 0; si < 128; ++si) a += sh_at[s2*128 + si]*__half2float(ep[(size_t)si*512]);
            } else {
                const float* ep = enc + ((size_t)(ab*256 + s2*128)*512 + e);
                #pragma unroll 8
                for(int si = 0; si < 128; ++si) a += sh_at[s2*128 + si]*ep[(size_t)si*512];
            }
            sh_ctxp[s2][e] = a;
        }
        __syncthreads();
        if(tid < 384){  // lin row: dw 0..127 = emb(relu), 128..383 = ctx
            float e0, e1;
            if(tid < 128){
                float x = xdec[ab*48 + t];
                e0 = fmaxf(x*embW[2*tid]   + embb[2*tid],   0.0f);
                e1 = fmaxf(x*embW[2*tid+1] + embb[2*tid+1], 0.0f);
            } else {
                int e = 2*(tid - 128);
                e0 = sh_ctxp[0][e]   + sh_ctxp[1][e];
                e1 = sh_ctxp[0][e+1] + sh_ctxp[1][e+1];
            }
            __half2 p = __floats2half2_rn(e0, e1);
            __hip_atomic_store(&linD[ab*384 + tid], __builtin_bit_cast(unsigned int, p),
                               __ATOMIC_RELAXED, AGENT);
        }
        gbar(cnt, 3*t + 0);

        // ================= PHASE B : LSTM1 (MFMA, 16-way K-split) =================
        {
            unsigned int pf[4][8];
            #pragma unroll
            for(int mt = 0; mt < 4; ++mt){
                const int row = 64*H + 16*mt + cl;
                #pragma unroll
                for(int kt = 0; kt < 2; ++kt){
                    const int d0 = w*32 + kt*16 + kg*4;
                    const unsigned int* src; int di;
                    if(d0 < 384){ src = linD + row*384; di = d0; }
                    else        { src = h1r  + row*128; di = d0 - 384; }
                    #pragma unroll
                    for(int j = 0; j < 4; ++j)
                        pf[mt][kt*4 + j] = __hip_atomic_load(&src[di + j], __ATOMIC_RELAXED, AGENT);
                }
            }
            #pragma unroll
            for(int mt = 0; mt < 4; ++mt){
                v4f acc = {0.0f, 0.0f, 0.0f, 0.0f};
                uint4 ua0 = make_uint4(pf[mt][0], pf[mt][1], pf[mt][2], pf[mt][3]);
                uint4 ua1 = make_uint4(pf[mt][4], pf[mt][5], pf[mt][6], pf[mt][7]);
                acc = __builtin_amdgcn_mfma_f32_16x16x32_f16(__builtin_bit_cast(v8h, ua0), wb1a, acc, 0, 0, 0);
                acc = __builtin_amdgcn_mfma_f32_16x16x32_f16(__builtin_bit_cast(v8h, ua1), wb1b, acc, 0, 0, 0);
                #pragma unroll
                for(int r = 0; r < 4; ++r) zb[w][kg*4 + r][cl] = acc[r];
                __syncthreads();
                if(w == mt){
                    v4f z = {0.0f, 0.0f, 0.0f, 0.0f};
                    #pragma unroll
                    for(int q = 0; q < 16; ++q) z += *(const v4f*)&zb[q][bl][uu*4];
                    float cn = fast_sigm(z.y + bf1)*c1r + fast_sigm(z.x + bi1)*fast_tanh(z.z + bg1);
                    c1r = cn;
                    float hn = fast_sigm(z.w + bo1)*fast_tanh(cn);
                    float hp = __shfl_xor(hn, 16);
                    if((uu & 1) == 0){
                        __half2 ph = __floats2half2_rn(hn, hp);
                        int bb = 64*H + 16*mt + bl;
                        __hip_atomic_store(&h1w[bb*128 + 2*NT + (uu >> 1)],
                                           __builtin_bit_cast(unsigned int, ph),
                                           __ATOMIC_RELAXED, AGENT);
                    }
                }
                __syncthreads();
            }
        }
        gbar(cnt, 3*t + 1);

        // ================= PHASE C : LSTM2 (MFMA, 16-way K-split) =================
        {
            unsigned int pf2[4][4];
            #pragma unroll
            for(int mt = 0; mt < 4; ++mt){
                const int row = 64*H + 16*mt + cl;
                const int d0 = w*16 + kg*4;
                const unsigned int* src; int di;
                if(d0 < 128){ src = h1w + row*128; di = d0; }
                else        { src = h2r + row*128; di = d0 - 128; }
                #pragma unroll
                for(int j = 0; j < 4; ++j)
                    pf2[mt][j] = __hip_atomic_load(&src[di + j], __ATOMIC_RELAXED, AGENT);
            }
            #pragma unroll
            for(int mt = 0; mt < 4; ++mt){
                v4f acc = {0.0f, 0.0f, 0.0f, 0.0f};
                uint4 ua = make_uint4(pf2[mt][0], pf2[mt][1], pf2[mt][2], pf2[mt][3]);
                acc = __builtin_amdgcn_mfma_f32_16x16x32_f16(__builtin_bit_cast(v8h, ua), wc1, acc, 0, 0, 0);
                #pragma unroll
                for(int r = 0; r < 4; ++r) zb[w][kg*4 + r][cl] = acc[r];
                __syncthreads();
                if(w == mt){
                    v4f z = {0.0f, 0.0f, 0.0f, 0.0f};
                    #pragma unroll
                    for(int q = 0; q < 16; ++q) z += *(const v4f*)&zb[q][bl][uu*4];
                    float cn = fast_sigm(z.y + bf2)*c2r + fast_sigm(z.x + bi2)*fast_tanh(z.z + bg2);
                    c2r = cn;
                    float hn = fast_sigm(z.w + bo2)*fast_tanh(cn);
                    float hp = __shfl_xor(hn, 16);
                    if((uu & 1) == 0){
                        __half2 ph = __floats2half2_rn(hn, hp);
                        int bb = 64*H + 16*mt + bl;
                        __hip_atomic_store(&h2w[bb*128 + 2*NT + (uu >> 1)],
                                           __builtin_bit_cast(unsigned int, ph),
                                           __ATOMIC_RELAXED, AGENT);
                    }
                }
                __syncthreads();
            }
        }
        gbar(cnt, 3*t + 2);
    }

    // final pred (t=47): h2 now at parity 0
    {
        float pv = 0.0f;
        if(tid < 128){
            unsigned int v = __hip_atomic_load(&h2d[ab*128 + tid], __ATOMIC_RELAXED, AGENT);
            float2 f = __half22float2(__builtin_bit_cast(__half2, v));
            pv = f.x*Wo[2*tid] + f.y*Wo[2*tid+1];
            #pragma unroll
            for(int off = 32; off >= 1; off >>= 1) pv += __shfl_xor(pv, off);
            if((tid & 63) == 0) sh_red[tid >> 6] = pv;
        }
        __syncthreads();
        if(tid == 0) out[ab*48 + 47] = sh_red[0] + sh_red[1] + bov;
    }
}

extern "C" void kernel_launch(void* const* d_in, const int* in_sizes, int n_in,
                              void* d_out, int out_size, void* d_ws, size_t ws_size,
                              hipStream_t stream)
{
    const float* xdec = (const float*)d_in[0];
    const float* h1_in= (const float*)d_in[1];
    const float* c1_in= (const float*)d_in[2];
    const float* h2_in= (const float*)d_in[3];
    const float* c2_in= (const float*)d_in[4];
    const float* enc  = (const float*)d_in[5];
    const float* embW = (const float*)d_in[6];
    const float* embb = (const float*)d_in[7];
    const float* W1   = (const float*)d_in[8];
    const float* b1   = (const float*)d_in[9];
    const float* W2   = (const float*)d_in[10];
    const float* b2   = (const float*)d_in[11];
    const float* V    = (const float*)d_in[12];
    const float* bV   = (const float*)d_in[13];
    const float* Wx1  = (const float*)d_in[14];
    const float* Wh1  = (const float*)d_in[15];
    const float* bl1  = (const float*)d_in[16];
    const float* Wx2  = (const float*)d_in[17];
    const float* Wh2  = (const float*)d_in[18];
    const float* bl2  = (const float*)d_in[19];
    const float* Wo   = (const float*)d_in[20];
    const float* bo   = (const float*)d_in[21];

    if(ws_size < WS_CORE) return;

    char* ws = (char*)d_ws;
    __half* keysH = (__half*)(ws + OFF_KEYSH);
    __half* WbtH  = (__half*)(ws + OFF_WBT);
    __half* WctH  = (__half*)(ws + OFF_WCT);
    float*  W1t   = (float*) (ws + OFF_W1T);
    unsigned int* linD = (unsigned int*)(ws + OFF_LIN);
    unsigned int* h1d  = (unsigned int*)(ws + OFF_H1);
    unsigned int* h2d  = (unsigned int*)(ws + OFF_H2);
    int*    cnt   = (int*)   (ws + OFF_CNT);
    __half* encH  = (__half*)(ws + OFF_ENCH);

    const int useEncH = (ws_size >= WS_FULL) ? 1 : 0;
    const long long total = useEncH ? 18448640LL : 1671424LL;

    hipLaunchKernelGGL(setup_kernel, dim3(4096), dim3(256), 0, stream,
        Wx1, Wh1, Wx2, Wh2, W1, h1_in, h2_in, enc,
        WbtH, WctH, W1t, h1d, h2d, cnt, encH, total);

    hipLaunchKernelGGL(keys_kernel, dim3(1024), dim3(256), 0, stream,
        enc, W1t, b1, keysH);

    hipLaunchKernelGGL(decoder_main, dim3(128), dim3(1024), 0, stream,
        xdec, embW, embb, W2, b2, V, bV, Wo, bo, bl1, bl2,
        c1_in, c2_in, enc, encH, keysH, WbtH, WctH,
        linD, h1d, h2d, cnt, (float*)d_out, useEncH);
}